// Round 9
// baseline (203.260 us; speedup 1.0000x reference)
//
#include <hip/hip_runtime.h>

// Geometry fixed by the reference: x [B=2, C=64, R_rot=6, charts=5, H=128, W=256] fp32.
#define RROT   6
#define CHARTS 5
#define CHART_STRIDE 32768LL                 // H*W = 128*256
#define ROT_STRIDE   163840LL                // 5*CHART_STRIDE
#define BC_STRIDE    983040LL                // 6*ROT_STRIDE

typedef float f4 __attribute__((ext_vector_type(4)));

// R4's pipelined grid-strided streaming copy with ONE change: loads are PLAIN
// (cached) while stores remain NON-TEMPORAL. R7 showed plain stores cost ~17%
// (write-allocate churn); plain loads produce no writeback traffic (lines stay
// clean) and may use the more efficient cached read path. Single-variable test.
__global__ __launch_bounds__(256) void copy_bulk(const f4* __restrict__ in,
                                                 f4* __restrict__ out,
                                                 long long n4) {
    const int t = threadIdx.x;
    const long long n_steps = n4 >> 10;               // granules / 1024
    const long long G = gridDim.x;
    long long s = blockIdx.x;
    if (s < n_steps) {
        long long b = (s << 10) + t;
        f4 a0 = in[b];
        f4 a1 = in[b + 256];
        f4 a2 = in[b + 512];
        f4 a3 = in[b + 768];
        for (;;) {
            long long s2 = s + G;
            if (s2 < n_steps) {
                long long b2 = (s2 << 10) + t;
                f4 c0 = in[b2];
                f4 c1 = in[b2 + 256];
                f4 c2 = in[b2 + 512];
                f4 c3 = in[b2 + 768];
                __builtin_nontemporal_store(a0, &out[b]);
                __builtin_nontemporal_store(a1, &out[b + 256]);
                __builtin_nontemporal_store(a2, &out[b + 512]);
                __builtin_nontemporal_store(a3, &out[b + 768]);
                a0 = c0; a1 = c1; a2 = c2; a3 = c3;
                s = s2; b = b2;
            } else {
                __builtin_nontemporal_store(a0, &out[b]);
                __builtin_nontemporal_store(a1, &out[b + 256]);
                __builtin_nontemporal_store(a2, &out[b + 512]);
                __builtin_nontemporal_store(a3, &out[b + 768]);
                break;
            }
        }
    }
    // Tail (n4 % 1024) — empty for this shape, kept for safety.
    long long tail = n_steps << 10;
    long long stride = G * blockDim.x;
    for (long long g = tail + (long long)blockIdx.x * blockDim.x + t; g < n4; g += stride)
        out[g] = in[g];
}

// One thread per (bc, chart): compute both pole means (6 rot x 5 neighbors)
// from the INPUT and overwrite the 12 pole entries in out. Stream-ordered
// after the copy, so the overwrite is race-free.
__global__ void pole_fix(const float* __restrict__ x,
                         float* __restrict__ out, int total) {
    int idx = blockIdx.x * blockDim.x + threadIdx.x;
    if (idx >= total) return;
    int c  = idx % CHARTS;
    int bc = idx / CHARTS;
    int cm = (c + CHARTS - 1) % CHARTS;

    const float* base = x + (long long)bc * BC_STRIDE;

    // V1 neighbors of pole (0,0): [c,1,0],[c,1,1],[c,0,1],[cm,127,128],[cm,127,127]
    const long long off1[5] = {
        c  * CHART_STRIDE + 256, c * CHART_STRIDE + 257, c * CHART_STRIDE + 1,
        cm * CHART_STRIDE + 32640, cm * CHART_STRIDE + 32639,
    };
    // V2 neighbors of pole (0,128): [c,1,128],[c,1,129],[c,0,129],[cm,127,255],[c,0,127]
    const long long off2[5] = {
        c  * CHART_STRIDE + 384, c * CHART_STRIDE + 385, c * CHART_STRIDE + 129,
        cm * CHART_STRIDE + 32767, c * CHART_STRIDE + 127,
    };

    float s1 = 0.0f, s2 = 0.0f;
    #pragma unroll
    for (int r = 0; r < RROT; ++r) {
        const float* rb = base + r * ROT_STRIDE;
        #pragma unroll
        for (int n = 0; n < 5; ++n) {
            s1 += rb[off1[n]];
            s2 += rb[off2[n]];
        }
    }
    float m1 = s1 * (1.0f / 30.0f);
    float m2 = s2 * (1.0f / 30.0f);

    float* obase = out + (long long)bc * BC_STRIDE + (long long)c * CHART_STRIDE;
    #pragma unroll
    for (int r = 0; r < RROT; ++r) {
        obase[r * ROT_STRIDE + 0]   = m1;
        obase[r * ROT_STRIDE + 128] = m2;
    }
}

extern "C" void kernel_launch(void* const* d_in, const int* in_sizes, int n_in,
                              void* d_out, int out_size, void* d_ws, size_t ws_size,
                              hipStream_t stream) {
    const float* x = (const float*)d_in[0];
    float* out = (float*)d_out;
    long long n4 = (long long)in_sizes[0] / 4;   // 31,457,280 granules

    // 2048 blocks x 15 grid-strided steps = 30,720 steps exactly; zero tail.
    copy_bulk<<<2048, 256, 0, stream>>>((const f4*)x, (f4*)out, n4);

    int bc = (int)((long long)in_sizes[0] / BC_STRIDE);  // 128
    int total = bc * CHARTS;                              // 640
    pole_fix<<<(total + 127) / 128, 128, 0, stream>>>(x, out, total);
}

// Round 10
// 180.153 us; speedup vs baseline: 1.1283x; 1.1283x over previous
//
#include <hip/hip_runtime.h>

// Geometry fixed by the reference: x [B=2, C=64, R_rot=6, charts=5, H=128, W=256] fp32.
#define RROT   6
#define CHARTS 5
#define CHART_STRIDE 32768LL                 // H*W = 128*256
#define ROT_STRIDE   163840LL                // 5*CHART_STRIDE
#define BC_STRIDE    983040LL                // 6*ROT_STRIDE

typedef float f4 __attribute__((ext_vector_type(4)));

// Best measured variant (R4, 180.5 us): software-pipelined, grid-strided,
// fully NON-TEMPORAL streaming copy. Each block-step covers 1024 float4
// granules (16 KB); the next step's 4 loads issue into a fresh register set
// BEFORE the current step's stores, so 8 loads stay in flight per thread.
// Measured matrix: NT/NT=180.5, plain/NT=203, plain/plain=211, any fused
// pole-fix variant=196-308 -> both NT hints load-bearing, fusion closed.
__global__ __launch_bounds__(256) void copy_bulk(const f4* __restrict__ in,
                                                 f4* __restrict__ out,
                                                 long long n4) {
    const int t = threadIdx.x;
    const long long n_steps = n4 >> 10;               // granules / 1024
    const long long G = gridDim.x;
    long long s = blockIdx.x;
    if (s < n_steps) {
        long long b = (s << 10) + t;
        f4 a0 = __builtin_nontemporal_load(&in[b]);
        f4 a1 = __builtin_nontemporal_load(&in[b + 256]);
        f4 a2 = __builtin_nontemporal_load(&in[b + 512]);
        f4 a3 = __builtin_nontemporal_load(&in[b + 768]);
        for (;;) {
            long long s2 = s + G;
            if (s2 < n_steps) {
                long long b2 = (s2 << 10) + t;
                f4 c0 = __builtin_nontemporal_load(&in[b2]);
                f4 c1 = __builtin_nontemporal_load(&in[b2 + 256]);
                f4 c2 = __builtin_nontemporal_load(&in[b2 + 512]);
                f4 c3 = __builtin_nontemporal_load(&in[b2 + 768]);
                __builtin_nontemporal_store(a0, &out[b]);
                __builtin_nontemporal_store(a1, &out[b + 256]);
                __builtin_nontemporal_store(a2, &out[b + 512]);
                __builtin_nontemporal_store(a3, &out[b + 768]);
                a0 = c0; a1 = c1; a2 = c2; a3 = c3;
                s = s2; b = b2;
            } else {
                __builtin_nontemporal_store(a0, &out[b]);
                __builtin_nontemporal_store(a1, &out[b + 256]);
                __builtin_nontemporal_store(a2, &out[b + 512]);
                __builtin_nontemporal_store(a3, &out[b + 768]);
                break;
            }
        }
    }
    // Tail (n4 % 1024) — empty for this shape, kept for safety.
    long long tail = n_steps << 10;
    long long stride = G * blockDim.x;
    for (long long g = tail + (long long)blockIdx.x * blockDim.x + t; g < n4; g += stride)
        out[g] = in[g];
}

// One thread per (bc, chart): compute both pole means (6 rot x 5 neighbors)
// from the INPUT and overwrite the 12 pole entries in out. Stream-ordered
// after the copy, so the overwrite is race-free.
__global__ void pole_fix(const float* __restrict__ x,
                         float* __restrict__ out, int total) {
    int idx = blockIdx.x * blockDim.x + threadIdx.x;
    if (idx >= total) return;
    int c  = idx % CHARTS;
    int bc = idx / CHARTS;
    int cm = (c + CHARTS - 1) % CHARTS;

    const float* base = x + (long long)bc * BC_STRIDE;

    // V1 neighbors of pole (0,0): [c,1,0],[c,1,1],[c,0,1],[cm,127,128],[cm,127,127]
    const long long off1[5] = {
        c  * CHART_STRIDE + 256, c * CHART_STRIDE + 257, c * CHART_STRIDE + 1,
        cm * CHART_STRIDE + 32640, cm * CHART_STRIDE + 32639,
    };
    // V2 neighbors of pole (0,128): [c,1,128],[c,1,129],[c,0,129],[cm,127,255],[c,0,127]
    const long long off2[5] = {
        c  * CHART_STRIDE + 384, c * CHART_STRIDE + 385, c * CHART_STRIDE + 129,
        cm * CHART_STRIDE + 32767, c * CHART_STRIDE + 127,
    };

    float s1 = 0.0f, s2 = 0.0f;
    #pragma unroll
    for (int r = 0; r < RROT; ++r) {
        const float* rb = base + r * ROT_STRIDE;
        #pragma unroll
        for (int n = 0; n < 5; ++n) {
            s1 += rb[off1[n]];
            s2 += rb[off2[n]];
        }
    }
    float m1 = s1 * (1.0f / 30.0f);
    float m2 = s2 * (1.0f / 30.0f);

    float* obase = out + (long long)bc * BC_STRIDE + (long long)c * CHART_STRIDE;
    #pragma unroll
    for (int r = 0; r < RROT; ++r) {
        obase[r * ROT_STRIDE + 0]   = m1;
        obase[r * ROT_STRIDE + 128] = m2;
    }
}

extern "C" void kernel_launch(void* const* d_in, const int* in_sizes, int n_in,
                              void* d_out, int out_size, void* d_ws, size_t ws_size,
                              hipStream_t stream) {
    const float* x = (const float*)d_in[0];
    float* out = (float*)d_out;
    long long n4 = (long long)in_sizes[0] / 4;   // 31,457,280 granules

    // 2048 blocks x 15 grid-strided steps = 30,720 steps exactly; zero tail.
    copy_bulk<<<2048, 256, 0, stream>>>((const f4*)x, (f4*)out, n4);

    int bc = (int)((long long)in_sizes[0] / BC_STRIDE);  // 128
    int total = bc * CHARTS;                              // 640
    pole_fix<<<(total + 127) / 128, 128, 0, stream>>>(x, out, total);
}